// Round 17
// baseline (101.894 us; speedup 1.0000x reference)
//
#include <hip/hip_runtime.h>
#include <hip/hip_bf16.h>

typedef __bf16 bf16_t;
typedef __bf16 bf16x8 __attribute__((ext_vector_type(8)));
typedef float  f32x2  __attribute__((ext_vector_type(2)));
typedef float  f32x4  __attribute__((ext_vector_type(4)));
typedef float  f32x16 __attribute__((ext_vector_type(16)));
typedef unsigned u32x2 __attribute__((ext_vector_type(2)));
typedef unsigned u32x4 __attribute__((ext_vector_type(4)));
typedef int    i32x8  __attribute__((ext_vector_type(8)));

#define B_ 8
#define C_ 256
#define L_ 4096
#define M_ 2048
#define INV_SQRT2f 0.70710678118654752440f
// q scale: 1/sqrt(C) * log2(e)  (softmax runs in log2 domain -> v_exp_f32 direct)
#define QSCALEf (0.0625f * 1.4426950408889634f)

typedef __attribute__((address_space(3))) void as3_void;
typedef __attribute__((address_space(1))) const void as1_cvoid;

__device__ __forceinline__ void gload_lds16(const void* g, void* l) {
    __builtin_amdgcn_global_load_lds((as1_cvoid*)g, (as3_void*)l, 16, 0, 0);
}

__device__ __forceinline__ const bf16x8* ldg8(const bf16_t* p) {
    return reinterpret_cast<const bf16x8*>(p);
}

__device__ __forceinline__ unsigned packbf(float a, float b) {
    unsigned short ua = __builtin_bit_cast(unsigned short, (bf16_t)a);
    unsigned short ub = __builtin_bit_cast(unsigned short, (bf16_t)b);
    return (unsigned)ua | ((unsigned)ub << 16);
}

// v_permlane32_swap_b32 — ONLY on operands with DISTINCT values.
__device__ __forceinline__ void pl32swapu(unsigned &a, unsigned &b) {
    asm("v_permlane32_swap_b32 %0, %1" : "+v"(a), "+v"(b));
}

// swap bits 3 and 4 (sigma c-permutation for K/Q; involution)
__device__ __forceinline__ int bs34(int v) {
    return (v & ~0x18) | ((v & 8) << 1) | ((v & 16) >> 1);
}

// pack 4 f32 -> 4 fp8 e4m3 bytes (ascending byte order)
__device__ __forceinline__ unsigned pk4fp8(float a, float b, float c, float d) {
    int u = __builtin_amdgcn_cvt_pk_fp8_f32(a, b, 0, false);
    u = __builtin_amdgcn_cvt_pk_fp8_f32(c, d, u, true);
    return (unsigned)u;
}

// ---------------- kernel 0: weight conversion f32 -> bf16 (once) ----------------
__global__ __launch_bounds__(256) void conv_w_kernel(
    const float* __restrict__ Wq, const float* __restrict__ Wk, const float* __restrict__ Wv,
    bf16_t* __restrict__ Wqb, bf16_t* __restrict__ Wkb, bf16_t* __restrict__ Wvb) {
    int idx = blockIdx.x * 256 + threadIdx.x;
    int which = idx >> 16;
    int off = idx & 65535;
    const float* src = (which == 0) ? Wq : ((which == 1) ? Wk : Wv);
    bf16_t* dst = (which == 0) ? Wqb : ((which == 1) ? Wkb : Wvb);
    dst[off] = (bf16_t)src[off];
}

// ================= kernel A: fused Haar + K-proj(fp8) + V-proj(fp8) =================
__global__ __launch_bounds__(256, 2) void kv_proj_kernel(
    const float* __restrict__ x, const bf16_t* __restrict__ Wk, const float* __restrict__ bk,
    const bf16_t* __restrict__ Wv, const float* __restrict__ bv,
    unsigned char* __restrict__ kb8, unsigned char* __restrict__ vb8) {
    __shared__ __align__(16) char smem[16384 + 33280];
    char* xh = smem;                           // [32][512B] swizzled bf16
    float* tile = (float*)(smem + 16384);      // f32 [64][130]

    const int t = threadIdx.x;
    const int wave = t >> 6, lane = t & 63;
    const int l31 = lane & 31, hi = lane >> 5;
    const int bid = blockIdx.x;
    const int b = bid & 7;
    const int mt = bid >> 3;        // 0..63
    const int m0 = mt * 32;

    // ---- phase 1: build xh (4 c-chunks of 64), reg-staged pipeline ----
    const int c2 = (t & 31) * 2;
    const int mg = t >> 5;
    const int lrow = t >> 5;
    const int lcp  = t & 31;
    f32x2 stage[8];
    {
        const float* xs = x + ((size_t)(b * C_) * L_) + 2 * m0;
#pragma unroll
        for (int j = 0; j < 8; ++j)
            stage[j] = *reinterpret_cast<const f32x2*>(xs + (size_t)(lrow + 8 * j) * L_ + lcp * 2);
    }
    for (int cc = 0; cc < 4; ++cc) {
        if (cc) __syncthreads();
#pragma unroll
        for (int j = 0; j < 8; ++j)
            *reinterpret_cast<f32x2*>(tile + (lrow + 8 * j) * 130 + lcp * 2) = stage[j];
        __syncthreads();
        if (cc < 3) {
            const float* xs = x + ((size_t)(b * C_ + (cc + 1) * 64) * L_) + 2 * m0;
#pragma unroll
            for (int j = 0; j < 8; ++j)
                stage[j] = *reinterpret_cast<const f32x2*>(xs + (size_t)(lrow + 8 * j) * L_ + lcp * 2);
        }
#pragma unroll
        for (int i = 0; i < 4; ++i) {
            int m = mg * 4 + i;
            f32x2 pa = *reinterpret_cast<const f32x2*>(tile + c2 * 130 + 2 * m);
            f32x2 pb = *reinterpret_cast<const f32x2*>(tile + (c2 + 1) * 130 + 2 * m);
            float va  = (pa[0] - pa[1]) * INV_SQRT2f;
            float vb2 = (pb[0] - pb[1]) * INV_SQRT2f;
            int byte = m * 512 + ((((cc * 64 + c2) * 2)) ^ ((m & 7) << 4));
            *reinterpret_cast<unsigned*>(xh + byte) = packbf(va, vb2);
        }
    }
    __syncthreads();

    // ---- phase 2: merged K-proj + V-proj (shared xh reads, bf16 weights) ----
    const int oq = wave;
    f32x16 kacc[2], vacc[2];
#pragma unroll
    for (int ob = 0; ob < 2; ++ob) {
        float bko = bk[(oq * 2 + ob) * 32 + l31];
#pragma unroll
        for (int r = 0; r < 16; ++r) { kacc[ob][r] = bko; vacc[ob][r] = 0.f; }
    }
    const int s0 = (l31 & 7) << 4;
#pragma unroll
    for (int ks = 0; ks < 16; ++ks) {
        int cb = (ks * 16 + hi * 8) * 2;
        bf16x8 xv = *reinterpret_cast<const bf16x8*>(xh + l31 * 512 + (cb ^ s0));
#pragma unroll
        for (int ob = 0; ob < 2; ++ob) {
            int o = (oq * 2 + ob) * 32 + l31;
            bf16x8 bw = *ldg8(Wk + (size_t)o * C_ + ks * 16 + hi * 8);
            kacc[ob] = __builtin_amdgcn_mfma_f32_32x32x16_bf16(xv, bw, kacc[ob], 0, 0, 0);
            bf16x8 aw = *ldg8(Wv + (size_t)o * C_ + ks * 16 + hi * 8);
            vacc[ob] = __builtin_amdgcn_mfma_f32_32x32x16_bf16(aw, xv, vacc[ob], 0, 0, 0);
        }
    }
    // K out: fp8, sigma-permuted channels. V out: fp8 [C][M], plain.
    unsigned char* kout8 = kb8 + (size_t)b * M_ * C_;
    unsigned char* vout8 = vb8 + (size_t)b * C_ * M_;
#pragma unroll
    for (int ob = 0; ob < 2; ++ob) {
        int o = (oq * 2 + ob) * 32 + l31;
        int g = bs34(o);
#pragma unroll
        for (int r = 0; r < 16; ++r) {
            int mloc = (r & 3) + 8 * (r >> 2) + 4 * hi;
            unsigned p = (unsigned)__builtin_amdgcn_cvt_pk_fp8_f32(kacc[ob][r], kacc[ob][r], 0, false);
            kout8[(size_t)(m0 + mloc) * C_ + g] = (unsigned char)(p & 0xFF);
        }
#pragma unroll
        for (int r = 0; r < 16; ++r) {
            int ov = (oq * 2 + ob) * 32 + (r & 3) + 8 * (r >> 2) + 4 * hi;
            float val = vacc[ob][r] + bv[ov];
            unsigned p = (unsigned)__builtin_amdgcn_cvt_pk_fp8_f32(val, val, 0, false);
            vout8[(size_t)ov * M_ + m0 + l31] = (unsigned char)(p & 0xFF);
        }
    }
}

// ================= kernel B: attention, fp8 S (MX K=64) and fp8 PV =================
#define KT 64
#define NT (M_ / KT)   // 32

// LDS map (main loop): K fp8 dbuf [0,32K) | V fp8 [c][72B] dbuf [32768, 69632)
// prologue: qt @0 (32K fp8), xt @32768 (64K), tile @98304; mlb @131072.
__global__ __launch_bounds__(512, 1) void attn_kernel(
    const bf16_t* __restrict__ Wq, const float* __restrict__ bq,
    const unsigned char* __restrict__ kb8, const unsigned char* __restrict__ vb8,
    const float* __restrict__ x, const float* __restrict__ gate, float* __restrict__ out) {
    __shared__ __align__(16) char smem[135168];
    char* Kbase_l = smem;                   // 32KB K fp8 dbuf / qt
    float* tile   = (float*)(smem + 98304); // prologue scratch

    const int t = threadIdx.x;
    const int wave = t >> 6, lane = t & 63;
    const int qg = wave & 3, mh = wave >> 2;
    const int l31 = lane & 31, hi = lane >> 5;
    const int bid = blockIdx.x;
    const int b = bid & 7;
    const int lt = bid >> 3;
    const int l0w = lt * 128 + qg * 32;

    i32x8 qfr[4];   // fp8 Q B-frags for MX K=64 S-MFMA (8 regs each)

    // ======== Q-projection prologue (bf16 GEMM, fp8 pack; QSCALE folded) ========
    {
        char* xt = smem + 32768;         // [128][512B] bf16 swizzled
        const int cp2 = (t & 31) * 2;
        const int lg = t >> 5;
        const int lrow = t >> 6;
        const int lcp  = t & 63;
        f32x2 stage[8];
        {
            const float* xs = x + ((size_t)(b * C_) * L_) + lt * 128;
#pragma unroll
            for (int j = 0; j < 8; ++j)
                stage[j] = *reinterpret_cast<const f32x2*>(xs + (size_t)(lrow + 8 * j) * L_ + lcp * 2);
        }
        for (int cc = 0; cc < 4; ++cc) {
            if (cc) __syncthreads();
#pragma unroll
            for (int j = 0; j < 8; ++j)
                *reinterpret_cast<f32x2*>(tile + (lrow + 8 * j) * 130 + lcp * 2) = stage[j];
            __syncthreads();
            if (cc < 3) {
                const float* xs = x + ((size_t)(b * C_ + (cc + 1) * 64) * L_) + lt * 128;
#pragma unroll
                for (int j = 0; j < 8; ++j)
                    stage[j] = *reinterpret_cast<const f32x2*>(xs + (size_t)(lrow + 8 * j) * L_ + lcp * 2);
            }
#pragma unroll
            for (int i = 0; i < 8; ++i) {
                int l = lg * 8 + i;
                float va  = tile[cp2 * 130 + l];
                float vb2 = tile[(cp2 + 1) * 130 + l];
                int byte = l * 512 + ((((cc * 64 + cp2) * 2)) ^ ((l & 7) << 4));
                *reinterpret_cast<unsigned*>(xt + byte) = packbf(va, vb2);
            }
        }
        __syncthreads();

        const int ow = wave * 32;
        f32x16 qacc[4];
#pragma unroll
        for (int lb = 0; lb < 4; ++lb)
#pragma unroll
            for (int r = 0; r < 16; ++r) qacc[lb][r] = 0.f;
#pragma unroll
        for (int ks = 0; ks < 16; ++ks) {
            bf16x8 aw = *ldg8(Wq + (size_t)(ow + l31) * C_ + ks * 16 + hi * 8);
#pragma unroll
            for (int lb = 0; lb < 4; ++lb) {
                int lrow2 = lb * 32 + l31;
                bf16x8 bx = *reinterpret_cast<const bf16x8*>(
                    xt + lrow2 * 512 + (((ks * 16 + hi * 8) * 2) ^ ((lrow2 & 7) << 4)));
                qacc[lb] = __builtin_amdgcn_mfma_f32_32x32x16_bf16(aw, bx, qacc[lb], 0, 0, 0);
            }
        }
        // qt: fp8 [128][256B], sigma-permuted c, swz=((l&7)<<4)
        char* qt = Kbase_l;
#pragma unroll
        for (int lb = 0; lb < 4; ++lb) {
            int l = lb * 32 + l31;
            int lsw = (l & 7) << 4;
#pragma unroll
            for (int q = 0; q < 4; ++q) {
                int o0 = ow + 4 * hi + 8 * q;
                f32x4 bq4 = *reinterpret_cast<const f32x4*>(bq + o0);
                unsigned w = pk4fp8((qacc[lb][q * 4 + 0] + bq4[0]) * QSCALEf,
                                    (qacc[lb][q * 4 + 1] + bq4[1]) * QSCALEf,
                                    (qacc[lb][q * 4 + 2] + bq4[2]) * QSCALEf,
                                    (qacc[lb][q * 4 + 3] + bq4[3]) * QSCALEf);
                int pos0 = bs34(o0);
                *reinterpret_cast<unsigned*>(qt + l * 256 + (pos0 ^ lsw)) = w;
            }
        }
        __syncthreads();
        const int qrow = qg * 32 + l31;
        const int qswz = (qrow & 7) << 4;
#pragma unroll
        for (int i = 0; i < 4; ++i) {
            u32x4 v0 = *reinterpret_cast<const u32x4*>(
                qt + qrow * 256 + (((2 * i) * 32 + hi * 16) ^ qswz));
            u32x4 v1 = *reinterpret_cast<const u32x4*>(
                qt + qrow * 256 + (((2 * i + 1) * 32 + hi * 16) ^ qswz));
            i32x8 q;
            q[0] = (int)v0[0]; q[1] = (int)v0[1]; q[2] = (int)v0[2]; q[3] = (int)v0[3];
            q[4] = (int)v1[0]; q[5] = (int)v1[1]; q[6] = (int)v1[2]; q[7] = (int)v1[3];
            qfr[i] = q;
        }
        __syncthreads();   // qfr everywhere; K/V regions may be overwritten
    }

    // ======== main flash loop ========
    const char* Kg = (const char*)(kb8 + (size_t)b * M_ * C_);   // fp8 [M][256B]
    int ksrc[2];
#pragma unroll
    for (int i = 0; i < 2; ++i) {
        int chunk = i * 8 + wave;
        int mr = chunk * 4 + (lane >> 4);
        ksrc[i] = mr * 256 + (((lane & 15) * 16) ^ ((mr & 7) << 4));
    }
    // V reg-stage geometry: fp8 [c][72B] rows, each lane stages 32B of one row
    const int vrow = wave * 32 + (lane >> 1);      // 0..255
    const int vhalf = (lane & 1) * 32;             // 0 / 32
    const char* VgRow = (const char*)(vb8 + (size_t)b * C_ * M_ + (size_t)vrow * M_);
    const int vdoff = vrow * 72 + vhalf;

    // prologue staging: K tile0 DMA + V tile0 reg-stage
#pragma unroll
    for (int i = 0; i < 2; ++i)
        gload_lds16(Kg + ksrc[i], Kbase_l + (i * 8 + wave) * 1024);
    {
        u32x4 s0 = *reinterpret_cast<const u32x4*>(VgRow + vhalf);
        u32x4 s1 = *reinterpret_cast<const u32x4*>(VgRow + vhalf + 16);
        char* vd = smem + 32768 + vdoff;
        u32x2 w;
        w[0] = s0[0]; w[1] = s0[1]; *reinterpret_cast<u32x2*>(vd) = w;
        w[0] = s0[2]; w[1] = s0[3]; *reinterpret_cast<u32x2*>(vd + 8) = w;
        w[0] = s1[0]; w[1] = s1[1]; *reinterpret_cast<u32x2*>(vd + 16) = w;
        w[0] = s1[2]; w[1] = s1[3]; *reinterpret_cast<u32x2*>(vd + 24) = w;
    }

    f32x16 acc[8];
#pragma unroll
    for (int cb = 0; cb < 8; ++cb)
#pragma unroll
        for (int r = 0; r < 16; ++r) acc[cb][r] = 0.f;
    float m_run = -INFINITY, l_run = 0.f;   // log2 domain; l_run lane-local partial

    asm volatile("s_waitcnt vmcnt(0) lgkmcnt(0)" ::: "memory");
    __builtin_amdgcn_s_barrier();
    asm volatile("" ::: "memory");

    for (int kt = 0; kt < NT; ++kt) {
        const int cur = kt & 1;
        u32x4 vstg0, vstg1;
        if (kt + 1 < NT) {
            const char* Kn = Kg + (size_t)(kt + 1) * 16384;
            char* Kd = Kbase_l + (cur ^ 1) * 16384;
#pragma unroll
            for (int i = 0; i < 2; ++i)
                gload_lds16(Kn + ksrc[i], Kd + (i * 8 + wave) * 1024);
            const char* src = VgRow + (size_t)(kt + 1) * 64 + vhalf;
            vstg0 = *reinterpret_cast<const u32x4*>(src);
            vstg1 = *reinterpret_cast<const u32x4*>(src + 16);
        }

        // ---- S = K' x Q (fp8, MX K=64, scale=1): 8 b128 reads -> 4 MFMA ----
        const char* Kc = Kbase_l + cur * 16384;
        const int mrow = mh * 32 + l31;
        const int msw = (mrow & 7) << 4;
        const int moff = mrow * 256;
        f32x16 s;
#pragma unroll
        for (int r = 0; r < 16; ++r) s[r] = 0.f;
        __builtin_amdgcn_s_setprio(1);
#pragma unroll
        for (int i = 0; i < 4; ++i) {
            u32x4 k0 = *reinterpret_cast<const u32x4*>(
                Kc + moff + (((2 * i) * 32 + hi * 16) ^ msw));
            u32x4 k1 = *reinterpret_cast<const u32x4*>(
                Kc + moff + (((2 * i + 1) * 32 + hi * 16) ^ msw));
            i32x8 a;
            a[0] = (int)k0[0]; a[1] = (int)k0[1]; a[2] = (int)k0[2]; a[3] = (int)k0[3];
            a[4] = (int)k1[0]; a[5] = (int)k1[1]; a[6] = (int)k1[2]; a[7] = (int)k1[3];
            s = __builtin_amdgcn_mfma_scale_f32_32x32x64_f8f6f4(
                    a, qfr[i], s, 0, 0, 0, 0x7F7F7F7F, 0, 0x7F7F7F7F);
        }
        __builtin_amdgcn_s_setprio(0);

        // ---- online softmax in log2 domain; defer-max THR=8 (2^8=256 < 448) ----
        float pv[16];
        float tm = -INFINITY;
#pragma unroll
        for (int r = 0; r < 16; ++r) {
            pv[r] = s[r];
            tm = fmaxf(tm, s[r]);
        }
        tm = fmaxf(tm, __shfl_xor(tm, 32));
        if (!__all(tm - m_run <= 8.0f)) {
            float m_new = fmaxf(m_run, tm);
            float corr = exp2f(m_run - m_new);
#pragma unroll
            for (int cb = 0; cb < 8; ++cb)
#pragma unroll
                for (int r = 0; r < 16; ++r) acc[cb][r] *= corr;
            l_run *= corr;
            m_run = m_new;
        }
        float rs = 0.f;
#pragma unroll
        for (int i = 0; i < 16; ++i) { pv[i] = exp2f(pv[i] - m_run); rs += pv[i]; }
        l_run += rs;   // lane-local partial; pair-reduced once before merge

        // ---- build P fp8 B-frags: 4 cvt_pk + 2 permlane swaps ----
        long pf0, pf1;
        {
            unsigned U0 = pk4fp8(pv[0], pv[1], pv[2], pv[3]);     // rows 0-3 (+4hi)
            unsigned U1 = pk4fp8(pv[4], pv[5], pv[6], pv[7]);     // rows 8-11
            unsigned U2 = pk4fp8(pv[8], pv[9], pv[10], pv[11]);   // rows 16-19
            unsigned U3 = pk4fp8(pv[12], pv[13], pv[14], pv[15]); // rows 24-27
            pl32swapu(U0, U1);
            pl32swapu(U2, U3);
            u32x2 p0; p0[0] = U0; p0[1] = U1;
            u32x2 p1; p1[0] = U2; p1[1] = U3;
            pf0 = __builtin_bit_cast(long, p0);
            pf1 = __builtin_bit_cast(long, p1);
        }

        // ---- PV (fp8): A = V[c][m] b64 reads, B = P regs ----
        const char* Vc = smem + 32768 + cur * 18432;
        __builtin_amdgcn_s_setprio(1);
#pragma unroll
        for (int ks2 = 0; ks2 < 2; ++ks2) {
            int mo = mh * 32 + ks2 * 16 + hi * 8;
            long pf = ks2 ? pf1 : pf0;
#pragma unroll
            for (int cb = 0; cb < 8; ++cb) {
                int c = cb * 32 + l31;
                long av = *reinterpret_cast<const long*>(Vc + c * 72 + mo);
                acc[cb] = __builtin_amdgcn_mfma_f32_32x32x16_fp8_fp8(av, pf, acc[cb], 0, 0, 0);
            }
        }
        __builtin_amdgcn_s_setprio(0);

        // ---- drain loads; write V[kt+1]; publish; barrier ----
        asm volatile("s_waitcnt vmcnt(0) lgkmcnt(0)" ::: "memory");
        if (kt + 1 < NT) {
            char* vd = smem + 32768 + (cur ^ 1) * 18432 + vdoff;
            u32x2 w;
            w[0] = vstg0[0]; w[1] = vstg0[1]; *reinterpret_cast<u32x2*>(vd) = w;
            w[0] = vstg0[2]; w[1] = vstg0[3]; *reinterpret_cast<u32x2*>(vd + 8) = w;
            w[0] = vstg1[0]; w[1] = vstg1[1]; *reinterpret_cast<u32x2*>(vd + 16) = w;
            w[0] = vstg1[2]; w[1] = vstg1[3]; *reinterpret_cast<u32x2*>(vd + 24) = w;
        }
        asm volatile("s_waitcnt lgkmcnt(0)" ::: "memory");
        __builtin_amdgcn_s_barrier();
        asm volatile("" ::: "memory");
    }

    // ---- collapse deferred lane-pair l_run, then split-K merge ----
    l_run += __shfl_xor(l_run, 32);

    f32x2* mlb = (f32x2*)(smem + 131072);
    f32x2 myml; myml[0] = m_run; myml[1] = l_run;
    mlb[wave * 64 + lane] = myml;
    __syncthreads();
    f32x2 pml = mlb[(wave ^ 4) * 64 + lane];
    float m_star = fmaxf(m_run, pml[0]);
    float f_self = exp2f(m_run - m_star);
    float f_peer = exp2f(pml[0] - m_star);
    float l_tot = l_run * f_self + pml[1] * f_peer;
#pragma unroll
    for (int cb = 0; cb < 8; ++cb)
#pragma unroll
        for (int r = 0; r < 16; ++r) acc[cb][r] *= f_self;

    char* xbuf = smem;
    const int myoff = (qg * 2 + mh) * 16384;
    __syncthreads();
#pragma unroll
    for (int cbl = 0; cbl < 4; ++cbl)
#pragma unroll
        for (int q = 0; q < 4; ++q) {
            f32x4 chunk;
#pragma unroll
            for (int j = 0; j < 4; ++j) {
                float a_lo = acc[cbl][q * 4 + j];
                float a_hi = acc[4 + cbl][q * 4 + j];
                chunk[j] = mh ? a_lo : a_hi;
            }
            *reinterpret_cast<f32x4*>(xbuf + myoff + (cbl * 4 + q) * 1024 + lane * 16) = chunk;
        }
    __syncthreads();

    const int poff = (qg * 2 + (1 - mh)) * 16384;
    float gt = tanhf(gate[0]);
    float scale = gt / l_tot;
    const float* xp = x + (size_t)b * C_ * L_;
    float* op = out + (size_t)b * C_ * L_;
    int lcol = l0w + l31;
    const int cbase = mh * 4;
#pragma unroll
    for (int cbl = 0; cbl < 4; ++cbl) {
#pragma unroll
        for (int q = 0; q < 4; ++q) {
            f32x4 pc = *reinterpret_cast<const f32x4*>(xbuf + poff + (cbl * 4 + q) * 1024 + lane * 16);
#pragma unroll
            for (int j = 0; j < 4; ++j) {
                float a_lo = acc[cbl][q * 4 + j];
                float a_hi = acc[4 + cbl][q * 4 + j];
                float mine = mh ? a_hi : a_lo;
                int c = (cbase + cbl) * 32 + j + 8 * q + 4 * hi;
                size_t idx = (size_t)c * L_ + lcol;
                op[idx] = (mine + pc[j]) * scale + xp[idx];
            }
        }
    }
}

extern "C" void kernel_launch(void* const* d_in, const int* in_sizes, int n_in,
                              void* d_out, int out_size, void* d_ws, size_t ws_size,
                              hipStream_t stream) {
    const float* x    = (const float*)d_in[0];
    const float* Wq   = (const float*)d_in[1];
    const float* bq   = (const float*)d_in[2];
    const float* Wk   = (const float*)d_in[3];
    const float* bk   = (const float*)d_in[4];
    const float* Wv   = (const float*)d_in[5];
    const float* bv   = (const float*)d_in[6];
    const float* gate = (const float*)d_in[7];
    float* out = (float*)d_out;

    char* ws = (char*)d_ws;
    const size_t szK8 = (size_t)B_ * M_ * C_;        // 4194304 (fp8)
    const size_t szV8 = (size_t)B_ * M_ * C_;        // 4194304 (fp8)
    const size_t szW  = (size_t)C_ * C_ * 2;         // 131072
    unsigned char* kbuf8 = (unsigned char*)(ws);
    unsigned char* vbuf8 = (unsigned char*)(ws + szK8);
    bf16_t* Wqb  = (bf16_t*)(ws + szK8 + szV8);
    bf16_t* Wkb  = (bf16_t*)(ws + szK8 + szV8 + szW);
    bf16_t* Wvb  = (bf16_t*)(ws + szK8 + szV8 + 2 * szW);

    conv_w_kernel<<<768, 256, 0, stream>>>(Wq, Wk, Wv, Wqb, Wkb, Wvb);
    kv_proj_kernel<<<512, 256, 0, stream>>>(x, Wkb, bk, Wvb, bv, kbuf8, vbuf8);
    attn_kernel<<<256, 512, 0, stream>>>(Wqb, bq, kbuf8, vbuf8, x, gate, out);
}

// Round 18
// 97.083 us; speedup vs baseline: 1.0496x; 1.0496x over previous
//
#include <hip/hip_runtime.h>
#include <hip/hip_bf16.h>

typedef __bf16 bf16_t;
typedef __bf16 bf16x8 __attribute__((ext_vector_type(8)));
typedef float  f32x2  __attribute__((ext_vector_type(2)));
typedef float  f32x4  __attribute__((ext_vector_type(4)));
typedef float  f32x16 __attribute__((ext_vector_type(16)));
typedef unsigned u32x2 __attribute__((ext_vector_type(2)));
typedef unsigned u32x4 __attribute__((ext_vector_type(4)));
typedef int    i32x8  __attribute__((ext_vector_type(8)));

#define B_ 8
#define C_ 256
#define L_ 4096
#define M_ 2048
#define INV_SQRT2f 0.70710678118654752440f
// q scale: 1/sqrt(C) * log2(e)  (softmax runs in log2 domain -> v_exp_f32 direct)
#define QSCALEf (0.0625f * 1.4426950408889634f)
// raw v_exp_f32 (2^x), NOT libm exp2f (multi-instruction precise path)
#define EXP2R(x) __builtin_amdgcn_exp2f(x)

typedef __attribute__((address_space(3))) void as3_void;
typedef __attribute__((address_space(1))) const void as1_cvoid;

__device__ __forceinline__ void gload_lds16(const void* g, void* l) {
    __builtin_amdgcn_global_load_lds((as1_cvoid*)g, (as3_void*)l, 16, 0, 0);
}

__device__ __forceinline__ const bf16x8* ldg8(const bf16_t* p) {
    return reinterpret_cast<const bf16x8*>(p);
}

__device__ __forceinline__ unsigned packbf(float a, float b) {
    unsigned short ua = __builtin_bit_cast(unsigned short, (bf16_t)a);
    unsigned short ub = __builtin_bit_cast(unsigned short, (bf16_t)b);
    return (unsigned)ua | ((unsigned)ub << 16);
}

// v_permlane32_swap_b32 — ONLY on operands with DISTINCT values.
__device__ __forceinline__ void pl32swapu(unsigned &a, unsigned &b) {
    asm("v_permlane32_swap_b32 %0, %1" : "+v"(a), "+v"(b));
}

// swap bits 3 and 4 (sigma c-permutation for K/Q; involution)
__device__ __forceinline__ int bs34(int v) {
    return (v & ~0x18) | ((v & 8) << 1) | ((v & 16) >> 1);
}

// pack 4 f32 -> 4 fp8 e4m3 bytes (ascending byte order)
__device__ __forceinline__ unsigned pk4fp8(float a, float b, float c, float d) {
    int u = __builtin_amdgcn_cvt_pk_fp8_f32(a, b, 0, false);
    u = __builtin_amdgcn_cvt_pk_fp8_f32(c, d, u, true);
    return (unsigned)u;
}

// ---------------- kernel 0: weight conversion f32 -> bf16 (once) ----------------
__global__ __launch_bounds__(256) void conv_w_kernel(
    const float* __restrict__ Wq, const float* __restrict__ Wk, const float* __restrict__ Wv,
    bf16_t* __restrict__ Wqb, bf16_t* __restrict__ Wkb, bf16_t* __restrict__ Wvb) {
    int idx = blockIdx.x * 256 + threadIdx.x;
    int which = idx >> 16;
    int off = idx & 65535;
    const float* src = (which == 0) ? Wq : ((which == 1) ? Wk : Wv);
    bf16_t* dst = (which == 0) ? Wqb : ((which == 1) ? Wkb : Wvb);
    dst[off] = (bf16_t)src[off];
}

// ================= kernel A: fused Haar + K-proj(fp8) + V-proj(fp8) =================
__global__ __launch_bounds__(256, 2) void kv_proj_kernel(
    const float* __restrict__ x, const bf16_t* __restrict__ Wk, const float* __restrict__ bk,
    const bf16_t* __restrict__ Wv, const float* __restrict__ bv,
    unsigned char* __restrict__ kb8, unsigned char* __restrict__ vb8) {
    __shared__ __align__(16) char smem[16384 + 33280];
    char* xh = smem;                           // [32][512B] swizzled bf16
    float* tile = (float*)(smem + 16384);      // f32 [64][130]

    const int t = threadIdx.x;
    const int wave = t >> 6, lane = t & 63;
    const int l31 = lane & 31, hi = lane >> 5;
    const int bid = blockIdx.x;
    const int b = bid & 7;
    const int mt = bid >> 3;        // 0..63
    const int m0 = mt * 32;

    // ---- phase 1: build xh (4 c-chunks of 64), reg-staged pipeline ----
    const int c2 = (t & 31) * 2;
    const int mg = t >> 5;
    const int lrow = t >> 5;
    const int lcp  = t & 31;
    f32x2 stage[8];
    {
        const float* xs = x + ((size_t)(b * C_) * L_) + 2 * m0;
#pragma unroll
        for (int j = 0; j < 8; ++j)
            stage[j] = *reinterpret_cast<const f32x2*>(xs + (size_t)(lrow + 8 * j) * L_ + lcp * 2);
    }
    for (int cc = 0; cc < 4; ++cc) {
        if (cc) __syncthreads();
#pragma unroll
        for (int j = 0; j < 8; ++j)
            *reinterpret_cast<f32x2*>(tile + (lrow + 8 * j) * 130 + lcp * 2) = stage[j];
        __syncthreads();
        if (cc < 3) {
            const float* xs = x + ((size_t)(b * C_ + (cc + 1) * 64) * L_) + 2 * m0;
#pragma unroll
            for (int j = 0; j < 8; ++j)
                stage[j] = *reinterpret_cast<const f32x2*>(xs + (size_t)(lrow + 8 * j) * L_ + lcp * 2);
        }
#pragma unroll
        for (int i = 0; i < 4; ++i) {
            int m = mg * 4 + i;
            f32x2 pa = *reinterpret_cast<const f32x2*>(tile + c2 * 130 + 2 * m);
            f32x2 pb = *reinterpret_cast<const f32x2*>(tile + (c2 + 1) * 130 + 2 * m);
            float va  = (pa[0] - pa[1]) * INV_SQRT2f;
            float vb2 = (pb[0] - pb[1]) * INV_SQRT2f;
            int byte = m * 512 + ((((cc * 64 + c2) * 2)) ^ ((m & 7) << 4));
            *reinterpret_cast<unsigned*>(xh + byte) = packbf(va, vb2);
        }
    }
    __syncthreads();

    // ---- phase 2: merged K-proj + V-proj (shared xh reads, bf16 weights) ----
    const int oq = wave;
    f32x16 kacc[2], vacc[2];
#pragma unroll
    for (int ob = 0; ob < 2; ++ob) {
        float bko = bk[(oq * 2 + ob) * 32 + l31];
#pragma unroll
        for (int r = 0; r < 16; ++r) { kacc[ob][r] = bko; vacc[ob][r] = 0.f; }
    }
    const int s0 = (l31 & 7) << 4;
#pragma unroll
    for (int ks = 0; ks < 16; ++ks) {
        int cb = (ks * 16 + hi * 8) * 2;
        bf16x8 xv = *reinterpret_cast<const bf16x8*>(xh + l31 * 512 + (cb ^ s0));
#pragma unroll
        for (int ob = 0; ob < 2; ++ob) {
            int o = (oq * 2 + ob) * 32 + l31;
            bf16x8 bw = *ldg8(Wk + (size_t)o * C_ + ks * 16 + hi * 8);
            kacc[ob] = __builtin_amdgcn_mfma_f32_32x32x16_bf16(xv, bw, kacc[ob], 0, 0, 0);
            bf16x8 aw = *ldg8(Wv + (size_t)o * C_ + ks * 16 + hi * 8);
            vacc[ob] = __builtin_amdgcn_mfma_f32_32x32x16_bf16(aw, xv, vacc[ob], 0, 0, 0);
        }
    }
    // K out: fp8, sigma-permuted channels. V out: fp8 [C][M], plain.
    unsigned char* kout8 = kb8 + (size_t)b * M_ * C_;
    unsigned char* vout8 = vb8 + (size_t)b * C_ * M_;
#pragma unroll
    for (int ob = 0; ob < 2; ++ob) {
        int o = (oq * 2 + ob) * 32 + l31;
        int g = bs34(o);
#pragma unroll
        for (int r = 0; r < 16; ++r) {
            int mloc = (r & 3) + 8 * (r >> 2) + 4 * hi;
            unsigned p = (unsigned)__builtin_amdgcn_cvt_pk_fp8_f32(kacc[ob][r], kacc[ob][r], 0, false);
            kout8[(size_t)(m0 + mloc) * C_ + g] = (unsigned char)(p & 0xFF);
        }
#pragma unroll
        for (int r = 0; r < 16; ++r) {
            int ov = (oq * 2 + ob) * 32 + (r & 3) + 8 * (r >> 2) + 4 * hi;
            float val = vacc[ob][r] + bv[ov];
            unsigned p = (unsigned)__builtin_amdgcn_cvt_pk_fp8_f32(val, val, 0, false);
            vout8[(size_t)ov * M_ + m0 + l31] = (unsigned char)(p & 0xFF);
        }
    }
}

// ================= kernel B: attention, fp8 S (MX K=64) and fp8 PV =================
#define KT 64
#define NT (M_ / KT)   // 32

// LDS map (main loop): K fp8 dbuf [0,32K) | V fp8 [c][72B] dbuf [32768, 69632)
// prologue: qt @0 (32K fp8), xt @32768 (64K), tile @98304; mlb @131072.
__global__ __launch_bounds__(512, 1) void attn_kernel(
    const bf16_t* __restrict__ Wq, const float* __restrict__ bq,
    const unsigned char* __restrict__ kb8, const unsigned char* __restrict__ vb8,
    const float* __restrict__ x, const float* __restrict__ gate, float* __restrict__ out) {
    __shared__ __align__(16) char smem[135168];
    char* Kbase_l = smem;                   // 32KB K fp8 dbuf / qt
    float* tile   = (float*)(smem + 98304); // prologue scratch

    const int t = threadIdx.x;
    const int wave = t >> 6, lane = t & 63;
    const int qg = wave & 3, mh = wave >> 2;
    const int l31 = lane & 31, hi = lane >> 5;
    const int bid = blockIdx.x;
    const int b = bid & 7;
    const int lt = bid >> 3;
    const int l0w = lt * 128 + qg * 32;

    i32x8 qfr[4];   // fp8 Q B-frags for MX K=64 S-MFMA (8 regs each)

    // ======== Q-projection prologue (bf16 GEMM, fp8 pack; QSCALE folded) ========
    {
        char* xt = smem + 32768;         // [128][512B] bf16 swizzled
        const int cp2 = (t & 31) * 2;
        const int lg = t >> 5;
        const int lrow = t >> 6;
        const int lcp  = t & 63;
        f32x2 stage[8];
        {
            const float* xs = x + ((size_t)(b * C_) * L_) + lt * 128;
#pragma unroll
            for (int j = 0; j < 8; ++j)
                stage[j] = *reinterpret_cast<const f32x2*>(xs + (size_t)(lrow + 8 * j) * L_ + lcp * 2);
        }
        for (int cc = 0; cc < 4; ++cc) {
            if (cc) __syncthreads();
#pragma unroll
            for (int j = 0; j < 8; ++j)
                *reinterpret_cast<f32x2*>(tile + (lrow + 8 * j) * 130 + lcp * 2) = stage[j];
            __syncthreads();
            if (cc < 3) {
                const float* xs = x + ((size_t)(b * C_ + (cc + 1) * 64) * L_) + lt * 128;
#pragma unroll
                for (int j = 0; j < 8; ++j)
                    stage[j] = *reinterpret_cast<const f32x2*>(xs + (size_t)(lrow + 8 * j) * L_ + lcp * 2);
            }
#pragma unroll
            for (int i = 0; i < 8; ++i) {
                int l = lg * 8 + i;
                float va  = tile[cp2 * 130 + l];
                float vb2 = tile[(cp2 + 1) * 130 + l];
                int byte = l * 512 + ((((cc * 64 + cp2) * 2)) ^ ((l & 7) << 4));
                *reinterpret_cast<unsigned*>(xt + byte) = packbf(va, vb2);
            }
        }
        __syncthreads();

        const int ow = wave * 32;
        f32x16 qacc[4];
#pragma unroll
        for (int lb = 0; lb < 4; ++lb)
#pragma unroll
            for (int r = 0; r < 16; ++r) qacc[lb][r] = 0.f;
#pragma unroll
        for (int ks = 0; ks < 16; ++ks) {
            bf16x8 aw = *ldg8(Wq + (size_t)(ow + l31) * C_ + ks * 16 + hi * 8);
#pragma unroll
            for (int lb = 0; lb < 4; ++lb) {
                int lrow2 = lb * 32 + l31;
                bf16x8 bx = *reinterpret_cast<const bf16x8*>(
                    xt + lrow2 * 512 + (((ks * 16 + hi * 8) * 2) ^ ((lrow2 & 7) << 4)));
                qacc[lb] = __builtin_amdgcn_mfma_f32_32x32x16_bf16(aw, bx, qacc[lb], 0, 0, 0);
            }
        }
        // qt: fp8 [128][256B], sigma-permuted c, swz=((l&7)<<4)
        char* qt = Kbase_l;
#pragma unroll
        for (int lb = 0; lb < 4; ++lb) {
            int l = lb * 32 + l31;
            int lsw = (l & 7) << 4;
#pragma unroll
            for (int q = 0; q < 4; ++q) {
                int o0 = ow + 4 * hi + 8 * q;
                f32x4 bq4 = *reinterpret_cast<const f32x4*>(bq + o0);
                unsigned w = pk4fp8((qacc[lb][q * 4 + 0] + bq4[0]) * QSCALEf,
                                    (qacc[lb][q * 4 + 1] + bq4[1]) * QSCALEf,
                                    (qacc[lb][q * 4 + 2] + bq4[2]) * QSCALEf,
                                    (qacc[lb][q * 4 + 3] + bq4[3]) * QSCALEf);
                int pos0 = bs34(o0);
                *reinterpret_cast<unsigned*>(qt + l * 256 + (pos0 ^ lsw)) = w;
            }
        }
        __syncthreads();
        const int qrow = qg * 32 + l31;
        const int qswz = (qrow & 7) << 4;
#pragma unroll
        for (int i = 0; i < 4; ++i) {
            u32x4 v0 = *reinterpret_cast<const u32x4*>(
                qt + qrow * 256 + (((2 * i) * 32 + hi * 16) ^ qswz));
            u32x4 v1 = *reinterpret_cast<const u32x4*>(
                qt + qrow * 256 + (((2 * i + 1) * 32 + hi * 16) ^ qswz));
            i32x8 q;
            q[0] = (int)v0[0]; q[1] = (int)v0[1]; q[2] = (int)v0[2]; q[3] = (int)v0[3];
            q[4] = (int)v1[0]; q[5] = (int)v1[1]; q[6] = (int)v1[2]; q[7] = (int)v1[3];
            qfr[i] = q;
        }
        __syncthreads();   // qfr everywhere; K/V regions may be overwritten
    }

    // ======== main flash loop ========
    const char* Kg = (const char*)(kb8 + (size_t)b * M_ * C_);   // fp8 [M][256B]
    int ksrc[2];
#pragma unroll
    for (int i = 0; i < 2; ++i) {
        int chunk = i * 8 + wave;
        int mr = chunk * 4 + (lane >> 4);
        ksrc[i] = mr * 256 + (((lane & 15) * 16) ^ ((mr & 7) << 4));
    }
    // V reg-stage geometry: fp8 [c][72B] rows, each lane stages 32B of one row
    const int vrow = wave * 32 + (lane >> 1);      // 0..255
    const int vhalf = (lane & 1) * 32;             // 0 / 32
    const char* VgRow = (const char*)(vb8 + (size_t)b * C_ * M_ + (size_t)vrow * M_);
    const int vdoff = vrow * 72 + vhalf;

    // prologue staging: K tile0 DMA + V tile0 reg-stage
#pragma unroll
    for (int i = 0; i < 2; ++i)
        gload_lds16(Kg + ksrc[i], Kbase_l + (i * 8 + wave) * 1024);
    {
        u32x4 s0 = *reinterpret_cast<const u32x4*>(VgRow + vhalf);
        u32x4 s1 = *reinterpret_cast<const u32x4*>(VgRow + vhalf + 16);
        char* vd = smem + 32768 + vdoff;
        u32x2 w;
        w[0] = s0[0]; w[1] = s0[1]; *reinterpret_cast<u32x2*>(vd) = w;
        w[0] = s0[2]; w[1] = s0[3]; *reinterpret_cast<u32x2*>(vd + 8) = w;
        w[0] = s1[0]; w[1] = s1[1]; *reinterpret_cast<u32x2*>(vd + 16) = w;
        w[0] = s1[2]; w[1] = s1[3]; *reinterpret_cast<u32x2*>(vd + 24) = w;
    }

    f32x16 acc[8];
#pragma unroll
    for (int cb = 0; cb < 8; ++cb)
#pragma unroll
        for (int r = 0; r < 16; ++r) acc[cb][r] = 0.f;
    float m_run = -INFINITY, l_run = 0.f;   // log2 domain; l_run lane-local partial

    asm volatile("s_waitcnt vmcnt(0) lgkmcnt(0)" ::: "memory");
    __builtin_amdgcn_s_barrier();
    asm volatile("" ::: "memory");

    for (int kt = 0; kt < NT; ++kt) {
        const int cur = kt & 1;
        u32x4 vstg0, vstg1;
        if (kt + 1 < NT) {
            const char* Kn = Kg + (size_t)(kt + 1) * 16384;
            char* Kd = Kbase_l + (cur ^ 1) * 16384;
#pragma unroll
            for (int i = 0; i < 2; ++i)
                gload_lds16(Kn + ksrc[i], Kd + (i * 8 + wave) * 1024);
            const char* src = VgRow + (size_t)(kt + 1) * 64 + vhalf;
            vstg0 = *reinterpret_cast<const u32x4*>(src);
            vstg1 = *reinterpret_cast<const u32x4*>(src + 16);
        }

        // ---- S = K' x Q (fp8, MX K=64, scale=1): 8 b128 reads -> 4 MFMA ----
        const char* Kc = Kbase_l + cur * 16384;
        const int mrow = mh * 32 + l31;
        const int msw = (mrow & 7) << 4;
        const int moff = mrow * 256;
        f32x16 s;
#pragma unroll
        for (int r = 0; r < 16; ++r) s[r] = 0.f;
        __builtin_amdgcn_s_setprio(1);
#pragma unroll
        for (int i = 0; i < 4; ++i) {
            u32x4 k0 = *reinterpret_cast<const u32x4*>(
                Kc + moff + (((2 * i) * 32 + hi * 16) ^ msw));
            u32x4 k1 = *reinterpret_cast<const u32x4*>(
                Kc + moff + (((2 * i + 1) * 32 + hi * 16) ^ msw));
            i32x8 a;
            a[0] = (int)k0[0]; a[1] = (int)k0[1]; a[2] = (int)k0[2]; a[3] = (int)k0[3];
            a[4] = (int)k1[0]; a[5] = (int)k1[1]; a[6] = (int)k1[2]; a[7] = (int)k1[3];
            s = __builtin_amdgcn_mfma_scale_f32_32x32x64_f8f6f4(
                    a, qfr[i], s, 0, 0, 0, 0x7F7F7F7F, 0, 0x7F7F7F7F);
        }
        __builtin_amdgcn_s_setprio(0);

        // ---- online softmax in log2 domain (raw v_exp_f32); THR=8 (2^8=256<448) ----
        float pv[16];
        float tm = -INFINITY;
#pragma unroll
        for (int r = 0; r < 16; ++r) {
            pv[r] = s[r];
            tm = fmaxf(tm, s[r]);
        }
        tm = fmaxf(tm, __shfl_xor(tm, 32));
        if (!__all(tm - m_run <= 8.0f)) {
            float m_new = fmaxf(m_run, tm);
            float corr = EXP2R(m_run - m_new);
#pragma unroll
            for (int cb = 0; cb < 8; ++cb)
#pragma unroll
                for (int r = 0; r < 16; ++r) acc[cb][r] *= corr;
            l_run *= corr;
            m_run = m_new;
        }
        float rs = 0.f;
#pragma unroll
        for (int i = 0; i < 16; ++i) { pv[i] = EXP2R(pv[i] - m_run); rs += pv[i]; }
        l_run += rs;   // lane-local partial; pair-reduced once before merge

        // ---- build P fp8 B-frags: 4 cvt_pk + 2 permlane swaps ----
        long pf0, pf1;
        {
            unsigned U0 = pk4fp8(pv[0], pv[1], pv[2], pv[3]);     // rows 0-3 (+4hi)
            unsigned U1 = pk4fp8(pv[4], pv[5], pv[6], pv[7]);     // rows 8-11
            unsigned U2 = pk4fp8(pv[8], pv[9], pv[10], pv[11]);   // rows 16-19
            unsigned U3 = pk4fp8(pv[12], pv[13], pv[14], pv[15]); // rows 24-27
            pl32swapu(U0, U1);
            pl32swapu(U2, U3);
            u32x2 p0; p0[0] = U0; p0[1] = U1;
            u32x2 p1; p1[0] = U2; p1[1] = U3;
            pf0 = __builtin_bit_cast(long, p0);
            pf1 = __builtin_bit_cast(long, p1);
        }

        // ---- PV (fp8): A = V[c][m] b64 reads, B = P regs ----
        const char* Vc = smem + 32768 + cur * 18432;
        __builtin_amdgcn_s_setprio(1);
#pragma unroll
        for (int ks2 = 0; ks2 < 2; ++ks2) {
            int mo = mh * 32 + ks2 * 16 + hi * 8;
            long pf = ks2 ? pf1 : pf0;
#pragma unroll
            for (int cb = 0; cb < 8; ++cb) {
                int c = cb * 32 + l31;
                long av = *reinterpret_cast<const long*>(Vc + c * 72 + mo);
                acc[cb] = __builtin_amdgcn_mfma_f32_32x32x16_fp8_fp8(av, pf, acc[cb], 0, 0, 0);
            }
        }
        __builtin_amdgcn_s_setprio(0);

        // ---- drain loads; write V[kt+1]; publish; barrier ----
        asm volatile("s_waitcnt vmcnt(0) lgkmcnt(0)" ::: "memory");
        if (kt + 1 < NT) {
            char* vd = smem + 32768 + (cur ^ 1) * 18432 + vdoff;
            u32x2 w;
            w[0] = vstg0[0]; w[1] = vstg0[1]; *reinterpret_cast<u32x2*>(vd) = w;
            w[0] = vstg0[2]; w[1] = vstg0[3]; *reinterpret_cast<u32x2*>(vd + 8) = w;
            w[0] = vstg1[0]; w[1] = vstg1[1]; *reinterpret_cast<u32x2*>(vd + 16) = w;
            w[0] = vstg1[2]; w[1] = vstg1[3]; *reinterpret_cast<u32x2*>(vd + 24) = w;
        }
        asm volatile("s_waitcnt lgkmcnt(0)" ::: "memory");
        __builtin_amdgcn_s_barrier();
        asm volatile("" ::: "memory");
    }

    // ---- collapse deferred lane-pair l_run, then split-K merge ----
    l_run += __shfl_xor(l_run, 32);

    f32x2* mlb = (f32x2*)(smem + 131072);
    f32x2 myml; myml[0] = m_run; myml[1] = l_run;
    mlb[wave * 64 + lane] = myml;
    __syncthreads();
    f32x2 pml = mlb[(wave ^ 4) * 64 + lane];
    float m_star = fmaxf(m_run, pml[0]);
    float f_self = EXP2R(m_run - m_star);
    float f_peer = EXP2R(pml[0] - m_star);
    float l_tot = l_run * f_self + pml[1] * f_peer;
#pragma unroll
    for (int cb = 0; cb < 8; ++cb)
#pragma unroll
        for (int r = 0; r < 16; ++r) acc[cb][r] *= f_self;

    char* xbuf = smem;
    const int myoff = (qg * 2 + mh) * 16384;
    __syncthreads();
#pragma unroll
    for (int cbl = 0; cbl < 4; ++cbl)
#pragma unroll
        for (int q = 0; q < 4; ++q) {
            f32x4 chunk;
#pragma unroll
            for (int j = 0; j < 4; ++j) {
                float a_lo = acc[cbl][q * 4 + j];
                float a_hi = acc[4 + cbl][q * 4 + j];
                chunk[j] = mh ? a_lo : a_hi;
            }
            *reinterpret_cast<f32x4*>(xbuf + myoff + (cbl * 4 + q) * 1024 + lane * 16) = chunk;
        }
    __syncthreads();

    const int poff = (qg * 2 + (1 - mh)) * 16384;
    float gt = tanhf(gate[0]);
    float scale = gt / l_tot;
    const float* xp = x + (size_t)b * C_ * L_;
    float* op = out + (size_t)b * C_ * L_;
    int lcol = l0w + l31;
    const int cbase = mh * 4;
#pragma unroll
    for (int cbl = 0; cbl < 4; ++cbl) {
#pragma unroll
        for (int q = 0; q < 4; ++q) {
            f32x4 pc = *reinterpret_cast<const f32x4*>(xbuf + poff + (cbl * 4 + q) * 1024 + lane * 16);
#pragma unroll
            for (int j = 0; j < 4; ++j) {
                float a_lo = acc[cbl][q * 4 + j];
                float a_hi = acc[4 + cbl][q * 4 + j];
                float mine = mh ? a_hi : a_lo;
                int c = (cbase + cbl) * 32 + j + 8 * q + 4 * hi;
                size_t idx = (size_t)c * L_ + lcol;
                op[idx] = (mine + pc[j]) * scale + xp[idx];
            }
        }
    }
}

extern "C" void kernel_launch(void* const* d_in, const int* in_sizes, int n_in,
                              void* d_out, int out_size, void* d_ws, size_t ws_size,
                              hipStream_t stream) {
    const float* x    = (const float*)d_in[0];
    const float* Wq   = (const float*)d_in[1];
    const float* bq   = (const float*)d_in[2];
    const float* Wk   = (const float*)d_in[3];
    const float* bk   = (const float*)d_in[4];
    const float* Wv   = (const float*)d_in[5];
    const float* bv   = (const float*)d_in[6];
    const float* gate = (const float*)d_in[7];
    float* out = (float*)d_out;

    char* ws = (char*)d_ws;
    const size_t szK8 = (size_t)B_ * M_ * C_;        // 4194304 (fp8)
    const size_t szV8 = (size_t)B_ * M_ * C_;        // 4194304 (fp8)
    const size_t szW  = (size_t)C_ * C_ * 2;         // 131072
    unsigned char* kbuf8 = (unsigned char*)(ws);
    unsigned char* vbuf8 = (unsigned char*)(ws + szK8);
    bf16_t* Wqb  = (bf16_t*)(ws + szK8 + szV8);
    bf16_t* Wkb  = (bf16_t*)(ws + szK8 + szV8 + szW);
    bf16_t* Wvb  = (bf16_t*)(ws + szK8 + szV8 + 2 * szW);

    conv_w_kernel<<<768, 256, 0, stream>>>(Wq, Wk, Wv, Wqb, Wkb, Wvb);
    kv_proj_kernel<<<512, 256, 0, stream>>>(x, Wkb, bk, Wvb, bv, kbuf8, vbuf8);
    attn_kernel<<<256, 512, 0, stream>>>(Wqb, bq, kbuf8, vbuf8, x, gate, out);
}

// Round 20
// 96.808 us; speedup vs baseline: 1.0525x; 1.0028x over previous
//
#include <hip/hip_runtime.h>
#include <hip/hip_bf16.h>

typedef __bf16 bf16_t;
typedef __bf16 bf16x8 __attribute__((ext_vector_type(8)));
typedef float  f32x2  __attribute__((ext_vector_type(2)));
typedef float  f32x4  __attribute__((ext_vector_type(4)));
typedef float  f32x16 __attribute__((ext_vector_type(16)));
typedef unsigned u32x2 __attribute__((ext_vector_type(2)));
typedef unsigned u32x4 __attribute__((ext_vector_type(4)));
typedef int    i32x8  __attribute__((ext_vector_type(8)));

#define B_ 8
#define C_ 256
#define L_ 4096
#define M_ 2048
#define INV_SQRT2f 0.70710678118654752440f
// q scale: 1/sqrt(C) * log2(e)  (softmax runs in log2 domain -> v_exp_f32 direct)
#define QSCALEf (0.0625f * 1.4426950408889634f)
// raw v_exp_f32 (2^x), NOT libm exp2f (multi-instruction precise path)
#define EXP2R(x) __builtin_amdgcn_exp2f(x)

typedef __attribute__((address_space(3))) void as3_void;
typedef __attribute__((address_space(1))) const void as1_cvoid;

__device__ __forceinline__ void gload_lds16(const void* g, void* l) {
    __builtin_amdgcn_global_load_lds((as1_cvoid*)g, (as3_void*)l, 16, 0, 0);
}

__device__ __forceinline__ const bf16x8* ldg8(const bf16_t* p) {
    return reinterpret_cast<const bf16x8*>(p);
}

__device__ __forceinline__ unsigned packbf(float a, float b) {
    unsigned short ua = __builtin_bit_cast(unsigned short, (bf16_t)a);
    unsigned short ub = __builtin_bit_cast(unsigned short, (bf16_t)b);
    return (unsigned)ua | ((unsigned)ub << 16);
}

// v_permlane32_swap_b32 — ONLY on operands with DISTINCT values.
__device__ __forceinline__ void pl32swapu(unsigned &a, unsigned &b) {
    asm("v_permlane32_swap_b32 %0, %1" : "+v"(a), "+v"(b));
}

// swap bits 3 and 4 (sigma c-permutation for K/Q; involution)
__device__ __forceinline__ int bs34(int v) {
    return (v & ~0x18) | ((v & 8) << 1) | ((v & 16) >> 1);
}

// pack 4 f32 -> 4 fp8 e4m3 bytes (ascending byte order)
__device__ __forceinline__ unsigned pk4fp8(float a, float b, float c, float d) {
    int u = __builtin_amdgcn_cvt_pk_fp8_f32(a, b, 0, false);
    u = __builtin_amdgcn_cvt_pk_fp8_f32(c, d, u, true);
    return (unsigned)u;
}

// ---------------- kernel 0: weight conversion f32 -> bf16 (once) ----------------
__global__ __launch_bounds__(256) void conv_w_kernel(
    const float* __restrict__ Wq, const float* __restrict__ Wk, const float* __restrict__ Wv,
    bf16_t* __restrict__ Wqb, bf16_t* __restrict__ Wkb, bf16_t* __restrict__ Wvb) {
    int idx = blockIdx.x * 256 + threadIdx.x;
    int which = idx >> 16;
    int off = idx & 65535;
    const float* src = (which == 0) ? Wq : ((which == 1) ? Wk : Wv);
    bf16_t* dst = (which == 0) ? Wqb : ((which == 1) ? Wkb : Wvb);
    dst[off] = (bf16_t)src[off];
}

// ================= kernel A: fused Haar + K-proj(fp8) + V-proj(fp8) =================
__global__ __launch_bounds__(256, 2) void kv_proj_kernel(
    const float* __restrict__ x, const bf16_t* __restrict__ Wk, const float* __restrict__ bk,
    const bf16_t* __restrict__ Wv, const float* __restrict__ bv,
    unsigned char* __restrict__ kb8, unsigned char* __restrict__ vb8) {
    __shared__ __align__(16) char smem[16384 + 33280];
    char* xh = smem;                           // [32][512B] swizzled bf16
    float* tile = (float*)(smem + 16384);      // f32 [64][130]

    const int t = threadIdx.x;
    const int wave = t >> 6, lane = t & 63;
    const int l31 = lane & 31, hi = lane >> 5;
    const int bid = blockIdx.x;
    const int b = bid & 7;
    const int mt = bid >> 3;        // 0..63
    const int m0 = mt * 32;

    // ---- phase 1: build xh (4 c-chunks of 64), reg-staged pipeline ----
    const int c2 = (t & 31) * 2;
    const int mg = t >> 5;
    const int lrow = t >> 5;
    const int lcp  = t & 31;
    f32x2 stage[8];
    {
        const float* xs = x + ((size_t)(b * C_) * L_) + 2 * m0;
#pragma unroll
        for (int j = 0; j < 8; ++j)
            stage[j] = *reinterpret_cast<const f32x2*>(xs + (size_t)(lrow + 8 * j) * L_ + lcp * 2);
    }
    for (int cc = 0; cc < 4; ++cc) {
        if (cc) __syncthreads();
#pragma unroll
        for (int j = 0; j < 8; ++j)
            *reinterpret_cast<f32x2*>(tile + (lrow + 8 * j) * 130 + lcp * 2) = stage[j];
        __syncthreads();
        if (cc < 3) {
            const float* xs = x + ((size_t)(b * C_ + (cc + 1) * 64) * L_) + 2 * m0;
#pragma unroll
            for (int j = 0; j < 8; ++j)
                stage[j] = *reinterpret_cast<const f32x2*>(xs + (size_t)(lrow + 8 * j) * L_ + lcp * 2);
        }
#pragma unroll
        for (int i = 0; i < 4; ++i) {
            int m = mg * 4 + i;
            f32x2 pa = *reinterpret_cast<const f32x2*>(tile + c2 * 130 + 2 * m);
            f32x2 pb = *reinterpret_cast<const f32x2*>(tile + (c2 + 1) * 130 + 2 * m);
            float va  = (pa[0] - pa[1]) * INV_SQRT2f;
            float vb2 = (pb[0] - pb[1]) * INV_SQRT2f;
            int byte = m * 512 + ((((cc * 64 + c2) * 2)) ^ ((m & 7) << 4));
            *reinterpret_cast<unsigned*>(xh + byte) = packbf(va, vb2);
        }
    }
    __syncthreads();

    // ---- phase 2: merged K-proj + V-proj (shared xh reads, bf16 weights) ----
    const int oq = wave;
    f32x16 kacc[2], vacc[2];
#pragma unroll
    for (int ob = 0; ob < 2; ++ob) {
        float bko = bk[(oq * 2 + ob) * 32 + l31];
#pragma unroll
        for (int r = 0; r < 16; ++r) { kacc[ob][r] = bko; vacc[ob][r] = 0.f; }
    }
    const int s0 = (l31 & 7) << 4;
#pragma unroll
    for (int ks = 0; ks < 16; ++ks) {
        int cb = (ks * 16 + hi * 8) * 2;
        bf16x8 xv = *reinterpret_cast<const bf16x8*>(xh + l31 * 512 + (cb ^ s0));
#pragma unroll
        for (int ob = 0; ob < 2; ++ob) {
            int o = (oq * 2 + ob) * 32 + l31;
            bf16x8 bw = *ldg8(Wk + (size_t)o * C_ + ks * 16 + hi * 8);
            kacc[ob] = __builtin_amdgcn_mfma_f32_32x32x16_bf16(xv, bw, kacc[ob], 0, 0, 0);
            bf16x8 aw = *ldg8(Wv + (size_t)o * C_ + ks * 16 + hi * 8);
            vacc[ob] = __builtin_amdgcn_mfma_f32_32x32x16_bf16(aw, xv, vacc[ob], 0, 0, 0);
        }
    }
    // K out: fp8, sigma-permuted channels. V out: fp8 [C][M], plain.
    unsigned char* kout8 = kb8 + (size_t)b * M_ * C_;
    unsigned char* vout8 = vb8 + (size_t)b * C_ * M_;
#pragma unroll
    for (int ob = 0; ob < 2; ++ob) {
        int o = (oq * 2 + ob) * 32 + l31;
        int g = bs34(o);
#pragma unroll
        for (int r = 0; r < 16; ++r) {
            int mloc = (r & 3) + 8 * (r >> 2) + 4 * hi;
            unsigned p = (unsigned)__builtin_amdgcn_cvt_pk_fp8_f32(kacc[ob][r], kacc[ob][r], 0, false);
            kout8[(size_t)(m0 + mloc) * C_ + g] = (unsigned char)(p & 0xFF);
        }
#pragma unroll
        for (int r = 0; r < 16; ++r) {
            int ov = (oq * 2 + ob) * 32 + (r & 3) + 8 * (r >> 2) + 4 * hi;
            float val = vacc[ob][r] + bv[ov];
            unsigned p = (unsigned)__builtin_amdgcn_cvt_pk_fp8_f32(val, val, 0, false);
            vout8[(size_t)ov * M_ + m0 + l31] = (unsigned char)(p & 0xFF);
        }
    }
}

// ================= kernel B: attention, fp8 S (MX K=64) and fp8 PV =================
#define KT 64
#define NT (M_ / KT)   // 32

// LDS map (main loop): K fp8 dbuf [0,32K) | V fp8 [c][72B] dbuf [32768, 69632)
// prologue: qt @0 (32K fp8), xt @32768 (64K), tile @98304; mlb @131072.
__global__ __launch_bounds__(512, 1) void attn_kernel(
    const bf16_t* __restrict__ Wq, const float* __restrict__ bq,
    const unsigned char* __restrict__ kb8, const unsigned char* __restrict__ vb8,
    const float* __restrict__ x, const float* __restrict__ gate, float* __restrict__ out) {
    __shared__ __align__(16) char smem[135168];
    char* Kbase_l = smem;                   // 32KB K fp8 dbuf / qt
    float* tile   = (float*)(smem + 98304); // prologue scratch

    const int t = threadIdx.x;
    const int wave = t >> 6, lane = t & 63;
    const int qg = wave & 3, mh = wave >> 2;
    const int l31 = lane & 31, hi = lane >> 5;
    const int bid = blockIdx.x;
    const int b = bid & 7;
    const int lt = bid >> 3;
    const int l0w = lt * 128 + qg * 32;

    i32x8 qfr[4];   // fp8 Q B-frags for MX K=64 S-MFMA (8 regs each)

    // ======== Q-projection prologue (bf16 GEMM, fp8 pack; QSCALE folded) ========
    {
        char* xt = smem + 32768;         // [128][512B] bf16 swizzled
        const int cp2 = (t & 31) * 2;
        const int lg = t >> 5;
        const int lrow = t >> 6;
        const int lcp  = t & 63;
        f32x2 stage[8];
        {
            const float* xs = x + ((size_t)(b * C_) * L_) + lt * 128;
#pragma unroll
            for (int j = 0; j < 8; ++j)
                stage[j] = *reinterpret_cast<const f32x2*>(xs + (size_t)(lrow + 8 * j) * L_ + lcp * 2);
        }
        for (int cc = 0; cc < 4; ++cc) {
            if (cc) __syncthreads();
#pragma unroll
            for (int j = 0; j < 8; ++j)
                *reinterpret_cast<f32x2*>(tile + (lrow + 8 * j) * 130 + lcp * 2) = stage[j];
            __syncthreads();
            if (cc < 3) {
                const float* xs = x + ((size_t)(b * C_ + (cc + 1) * 64) * L_) + lt * 128;
#pragma unroll
                for (int j = 0; j < 8; ++j)
                    stage[j] = *reinterpret_cast<const f32x2*>(xs + (size_t)(lrow + 8 * j) * L_ + lcp * 2);
            }
#pragma unroll
            for (int i = 0; i < 8; ++i) {
                int l = lg * 8 + i;
                float va  = tile[cp2 * 130 + l];
                float vb2 = tile[(cp2 + 1) * 130 + l];
                int byte = l * 512 + ((((cc * 64 + cp2) * 2)) ^ ((l & 7) << 4));
                *reinterpret_cast<unsigned*>(xt + byte) = packbf(va, vb2);
            }
        }
        __syncthreads();

        const int ow = wave * 32;
        f32x16 qacc[4];
#pragma unroll
        for (int lb = 0; lb < 4; ++lb)
#pragma unroll
            for (int r = 0; r < 16; ++r) qacc[lb][r] = 0.f;
#pragma unroll
        for (int ks = 0; ks < 16; ++ks) {
            bf16x8 aw = *ldg8(Wq + (size_t)(ow + l31) * C_ + ks * 16 + hi * 8);
#pragma unroll
            for (int lb = 0; lb < 4; ++lb) {
                int lrow2 = lb * 32 + l31;
                bf16x8 bx = *reinterpret_cast<const bf16x8*>(
                    xt + lrow2 * 512 + (((ks * 16 + hi * 8) * 2) ^ ((lrow2 & 7) << 4)));
                qacc[lb] = __builtin_amdgcn_mfma_f32_32x32x16_bf16(aw, bx, qacc[lb], 0, 0, 0);
            }
        }
        // qt: fp8 [128][256B], sigma-permuted c, swz=((l&7)<<4)
        char* qt = Kbase_l;
#pragma unroll
        for (int lb = 0; lb < 4; ++lb) {
            int l = lb * 32 + l31;
            int lsw = (l & 7) << 4;
#pragma unroll
            for (int q = 0; q < 4; ++q) {
                int o0 = ow + 4 * hi + 8 * q;
                f32x4 bq4 = *reinterpret_cast<const f32x4*>(bq + o0);
                unsigned w = pk4fp8((qacc[lb][q * 4 + 0] + bq4[0]) * QSCALEf,
                                    (qacc[lb][q * 4 + 1] + bq4[1]) * QSCALEf,
                                    (qacc[lb][q * 4 + 2] + bq4[2]) * QSCALEf,
                                    (qacc[lb][q * 4 + 3] + bq4[3]) * QSCALEf);
                int pos0 = bs34(o0);
                *reinterpret_cast<unsigned*>(qt + l * 256 + (pos0 ^ lsw)) = w;
            }
        }
        __syncthreads();
        const int qrow = qg * 32 + l31;
        const int qswz = (qrow & 7) << 4;
#pragma unroll
        for (int i = 0; i < 4; ++i) {
            u32x4 v0 = *reinterpret_cast<const u32x4*>(
                qt + qrow * 256 + (((2 * i) * 32 + hi * 16) ^ qswz));
            u32x4 v1 = *reinterpret_cast<const u32x4*>(
                qt + qrow * 256 + (((2 * i + 1) * 32 + hi * 16) ^ qswz));
            i32x8 q;
            q[0] = (int)v0[0]; q[1] = (int)v0[1]; q[2] = (int)v0[2]; q[3] = (int)v0[3];
            q[4] = (int)v1[0]; q[5] = (int)v1[1]; q[6] = (int)v1[2]; q[7] = (int)v1[3];
            qfr[i] = q;
        }
        __syncthreads();   // qfr everywhere; K/V regions may be overwritten
    }

    // ======== main flash loop ========
    const char* Kg = (const char*)(kb8 + (size_t)b * M_ * C_);   // fp8 [M][256B]
    int ksrc[2];
#pragma unroll
    for (int i = 0; i < 2; ++i) {
        int chunk = i * 8 + wave;
        int mr = chunk * 4 + (lane >> 4);
        ksrc[i] = mr * 256 + (((lane & 15) * 16) ^ ((mr & 7) << 4));
    }
    // V reg-stage geometry: fp8 [c][72B] rows, each lane stages 32B of one row
    const int vrow = wave * 32 + (lane >> 1);      // 0..255
    const int vhalf = (lane & 1) * 32;             // 0 / 32
    const char* VgRow = (const char*)(vb8 + (size_t)b * C_ * M_ + (size_t)vrow * M_);
    const int vdoff = vrow * 72 + vhalf;

    // prologue staging: K tile0 DMA + V tile0 reg-stage
#pragma unroll
    for (int i = 0; i < 2; ++i)
        gload_lds16(Kg + ksrc[i], Kbase_l + (i * 8 + wave) * 1024);
    {
        u32x4 s0 = *reinterpret_cast<const u32x4*>(VgRow + vhalf);
        u32x4 s1 = *reinterpret_cast<const u32x4*>(VgRow + vhalf + 16);
        char* vd = smem + 32768 + vdoff;
        u32x2 w;
        w[0] = s0[0]; w[1] = s0[1]; *reinterpret_cast<u32x2*>(vd) = w;
        w[0] = s0[2]; w[1] = s0[3]; *reinterpret_cast<u32x2*>(vd + 8) = w;
        w[0] = s1[0]; w[1] = s1[1]; *reinterpret_cast<u32x2*>(vd + 16) = w;
        w[0] = s1[2]; w[1] = s1[3]; *reinterpret_cast<u32x2*>(vd + 24) = w;
    }

    f32x16 acc[8];
#pragma unroll
    for (int cb = 0; cb < 8; ++cb)
#pragma unroll
        for (int r = 0; r < 16; ++r) acc[cb][r] = 0.f;
    float m_run = -INFINITY, l_run = 0.f;   // log2 domain; l_run lane-local partial

    asm volatile("s_waitcnt vmcnt(0) lgkmcnt(0)" ::: "memory");
    __builtin_amdgcn_s_barrier();
    asm volatile("" ::: "memory");

    for (int kt = 0; kt < NT; ++kt) {
        const int cur = kt & 1;
        u32x4 vstg0, vstg1;
        if (kt + 1 < NT) {
            const char* Kn = Kg + (size_t)(kt + 1) * 16384;
            char* Kd = Kbase_l + (cur ^ 1) * 16384;
#pragma unroll
            for (int i = 0; i < 2; ++i)
                gload_lds16(Kn + ksrc[i], Kd + (i * 8 + wave) * 1024);
            const char* src = VgRow + (size_t)(kt + 1) * 64 + vhalf;
            vstg0 = *reinterpret_cast<const u32x4*>(src);
            vstg1 = *reinterpret_cast<const u32x4*>(src + 16);
        }

        // ---- S = K' x Q (fp8, MX K=64, scale=1): 8 b128 reads -> 4 MFMA ----
        const char* Kc = Kbase_l + cur * 16384;
        const int mrow = mh * 32 + l31;
        const int msw = (mrow & 7) << 4;
        const int moff = mrow * 256;
        f32x16 s;
#pragma unroll
        for (int r = 0; r < 16; ++r) s[r] = 0.f;
        __builtin_amdgcn_s_setprio(1);
#pragma unroll
        for (int i = 0; i < 4; ++i) {
            u32x4 k0 = *reinterpret_cast<const u32x4*>(
                Kc + moff + (((2 * i) * 32 + hi * 16) ^ msw));
            u32x4 k1 = *reinterpret_cast<const u32x4*>(
                Kc + moff + (((2 * i + 1) * 32 + hi * 16) ^ msw));
            i32x8 a;
            a[0] = (int)k0[0]; a[1] = (int)k0[1]; a[2] = (int)k0[2]; a[3] = (int)k0[3];
            a[4] = (int)k1[0]; a[5] = (int)k1[1]; a[6] = (int)k1[2]; a[7] = (int)k1[3];
            s = __builtin_amdgcn_mfma_scale_f32_32x32x64_f8f6f4(
                    a, qfr[i], s, 0, 0, 0, 0x7F7F7F7F, 0, 0x7F7F7F7F);
        }
        __builtin_amdgcn_s_setprio(0);

        // ---- online softmax in log2 domain (raw v_exp_f32); THR=8 (2^8=256<448) ----
        float pv[16];
        float tm = -INFINITY;
#pragma unroll
        for (int r = 0; r < 16; ++r) {
            pv[r] = s[r];
            tm = fmaxf(tm, s[r]);
        }
        tm = fmaxf(tm, __shfl_xor(tm, 32));
        if (!__all(tm - m_run <= 8.0f)) {
            float m_new = fmaxf(m_run, tm);
            float corr = EXP2R(m_run - m_new);
#pragma unroll
            for (int cb = 0; cb < 8; ++cb)
#pragma unroll
                for (int r = 0; r < 16; ++r) acc[cb][r] *= corr;
            l_run *= corr;
            m_run = m_new;
        }
        float rs = 0.f;
#pragma unroll
        for (int i = 0; i < 16; ++i) { pv[i] = EXP2R(pv[i] - m_run); rs += pv[i]; }
        l_run += rs;   // lane-local partial; pair-reduced once before merge

        // ---- build P fp8 B-frags: 4 cvt_pk + 2 permlane swaps ----
        long pf0, pf1;
        {
            unsigned U0 = pk4fp8(pv[0], pv[1], pv[2], pv[3]);     // rows 0-3 (+4hi)
            unsigned U1 = pk4fp8(pv[4], pv[5], pv[6], pv[7]);     // rows 8-11
            unsigned U2 = pk4fp8(pv[8], pv[9], pv[10], pv[11]);   // rows 16-19
            unsigned U3 = pk4fp8(pv[12], pv[13], pv[14], pv[15]); // rows 24-27
            pl32swapu(U0, U1);
            pl32swapu(U2, U3);
            u32x2 p0; p0[0] = U0; p0[1] = U1;
            u32x2 p1; p1[0] = U2; p1[1] = U3;
            pf0 = __builtin_bit_cast(long, p0);
            pf1 = __builtin_bit_cast(long, p1);
        }

        // ---- PV (fp8): A = V[c][m] b64 reads, B = P regs ----
        const char* Vc = smem + 32768 + cur * 18432;
        __builtin_amdgcn_s_setprio(1);
#pragma unroll
        for (int ks2 = 0; ks2 < 2; ++ks2) {
            int mo = mh * 32 + ks2 * 16 + hi * 8;
            long pf = ks2 ? pf1 : pf0;
#pragma unroll
            for (int cb = 0; cb < 8; ++cb) {
                int c = cb * 32 + l31;
                long av = *reinterpret_cast<const long*>(Vc + c * 72 + mo);
                acc[cb] = __builtin_amdgcn_mfma_f32_32x32x16_fp8_fp8(av, pf, acc[cb], 0, 0, 0);
            }
        }
        __builtin_amdgcn_s_setprio(0);

        // ---- drain loads; write V[kt+1]; publish; barrier ----
        asm volatile("s_waitcnt vmcnt(0) lgkmcnt(0)" ::: "memory");
        if (kt + 1 < NT) {
            char* vd = smem + 32768 + (cur ^ 1) * 18432 + vdoff;
            u32x2 w;
            w[0] = vstg0[0]; w[1] = vstg0[1]; *reinterpret_cast<u32x2*>(vd) = w;
            w[0] = vstg0[2]; w[1] = vstg0[3]; *reinterpret_cast<u32x2*>(vd + 8) = w;
            w[0] = vstg1[0]; w[1] = vstg1[1]; *reinterpret_cast<u32x2*>(vd + 16) = w;
            w[0] = vstg1[2]; w[1] = vstg1[3]; *reinterpret_cast<u32x2*>(vd + 24) = w;
        }
        asm volatile("s_waitcnt lgkmcnt(0)" ::: "memory");
        __builtin_amdgcn_s_barrier();
        asm volatile("" ::: "memory");
    }

    // ---- collapse deferred lane-pair l_run, then split-K merge ----
    l_run += __shfl_xor(l_run, 32);

    f32x2* mlb = (f32x2*)(smem + 131072);
    f32x2 myml; myml[0] = m_run; myml[1] = l_run;
    mlb[wave * 64 + lane] = myml;
    __syncthreads();
    f32x2 pml = mlb[(wave ^ 4) * 64 + lane];
    float m_star = fmaxf(m_run, pml[0]);
    float f_self = EXP2R(m_run - m_star);
    float f_peer = EXP2R(pml[0] - m_star);
    float l_tot = l_run * f_self + pml[1] * f_peer;
#pragma unroll
    for (int cb = 0; cb < 8; ++cb)
#pragma unroll
        for (int r = 0; r < 16; ++r) acc[cb][r] *= f_self;

    char* xbuf = smem;
    const int myoff = (qg * 2 + mh) * 16384;
    __syncthreads();
#pragma unroll
    for (int cbl = 0; cbl < 4; ++cbl)
#pragma unroll
        for (int q = 0; q < 4; ++q) {
            f32x4 chunk;
#pragma unroll
            for (int j = 0; j < 4; ++j) {
                float a_lo = acc[cbl][q * 4 + j];
                float a_hi = acc[4 + cbl][q * 4 + j];
                chunk[j] = mh ? a_lo : a_hi;
            }
            *reinterpret_cast<f32x4*>(xbuf + myoff + (cbl * 4 + q) * 1024 + lane * 16) = chunk;
        }
    __syncthreads();

    const int poff = (qg * 2 + (1 - mh)) * 16384;
    float gt = tanhf(gate[0]);
    float scale = gt / l_tot;
    const float* xp = x + (size_t)b * C_ * L_;
    float* op = out + (size_t)b * C_ * L_;
    int lcol = l0w + l31;
    const int cbase = mh * 4;
#pragma unroll
    for (int cbl = 0; cbl < 4; ++cbl) {
#pragma unroll
        for (int q = 0; q < 4; ++q) {
            f32x4 pc = *reinterpret_cast<const f32x4*>(xbuf + poff + (cbl * 4 + q) * 1024 + lane * 16);
#pragma unroll
            for (int j = 0; j < 4; ++j) {
                float a_lo = acc[cbl][q * 4 + j];
                float a_hi = acc[4 + cbl][q * 4 + j];
                float mine = mh ? a_hi : a_lo;
                int c = (cbase + cbl) * 32 + j + 8 * q + 4 * hi;
                size_t idx = (size_t)c * L_ + lcol;
                op[idx] = (mine + pc[j]) * scale + xp[idx];
            }
        }
    }
}

extern "C" void kernel_launch(void* const* d_in, const int* in_sizes, int n_in,
                              void* d_out, int out_size, void* d_ws, size_t ws_size,
                              hipStream_t stream) {
    const float* x    = (const float*)d_in[0];
    const float* Wq   = (const float*)d_in[1];
    const float* bq   = (const float*)d_in[2];
    const float* Wk   = (const float*)d_in[3];
    const float* bk   = (const float*)d_in[4];
    const float* Wv   = (const float*)d_in[5];
    const float* bv   = (const float*)d_in[6];
    const float* gate = (const float*)d_in[7];
    float* out = (float*)d_out;

    char* ws = (char*)d_ws;
    const size_t szK8 = (size_t)B_ * M_ * C_;        // 4194304 (fp8)
    const size_t szV8 = (size_t)B_ * M_ * C_;        // 4194304 (fp8)
    const size_t szW  = (size_t)C_ * C_ * 2;         // 131072
    unsigned char* kbuf8 = (unsigned char*)(ws);
    unsigned char* vbuf8 = (unsigned char*)(ws + szK8);
    bf16_t* Wqb  = (bf16_t*)(ws + szK8 + szV8);
    bf16_t* Wkb  = (bf16_t*)(ws + szK8 + szV8 + szW);
    bf16_t* Wvb  = (bf16_t*)(ws + szK8 + szV8 + 2 * szW);

    conv_w_kernel<<<768, 256, 0, stream>>>(Wq, Wk, Wv, Wqb, Wkb, Wvb);
    kv_proj_kernel<<<512, 256, 0, stream>>>(x, Wkb, bk, Wvb, bv, kbuf8, vbuf8);
    attn_kernel<<<256, 512, 0, stream>>>(Wqb, bq, kbuf8, vbuf8, x, gate, out);
}